// Round 2
// baseline (2112.061 us; speedup 1.0000x reference)
//
#include <hip/hip_runtime.h>

// Problem constants: B=4, T=2048, H=16, K=128, V=128
constexpr int Bc = 4, Tc = 2048, Hc = 16, Kc = 128, Vc = 128;
constexpr int CHUNK = 64, NCc = Tc / CHUNK;  // 32 chunks
constexpr float EPSc = 1e-6f;
constexpr float SCALEc = 0.08838834764831845f; // 128^-0.5

__device__ __forceinline__ float rsqrt_nr(float s) {
  float r = rsqrtf(s);
  r = r * (1.5f - 0.5f * s * r * r);
  return r;
}

// 5-bit XOR swizzle for 128-float LDS rows read as 8 strided float4 frags
__device__ __forceinline__ int swz5(int c4) { return c4 ^ (c4 >> 2); }

// ---------------- Phase 1a: normalize q,k and write [bh][t][k] layout ------
__global__ __launch_bounds__(256) void norm_qk_t(const float* __restrict__ q,
                                                 const float* __restrict__ k,
                                                 float* __restrict__ qh,
                                                 float* __restrict__ kh) {
  int row = blockIdx.x * 4 + (threadIdx.x >> 6);  // (b*T+t)*H+h
  int lane = threadIdx.x & 63;
  int b = row >> 15;            // / (T*H)=32768
  int rem = row & 32767;
  int t = rem >> 4;             // / H=16
  int h = rem & 15;
  const float2 vq = ((const float2*)(q + (size_t)row * Kc))[lane];
  const float2 vk = ((const float2*)(k + (size_t)row * Kc))[lane];
  float sq = vq.x * vq.x + vq.y * vq.y;
  float sk = vk.x * vk.x + vk.y * vk.y;
#pragma unroll
  for (int m = 1; m < 64; m <<= 1) {
    sq += __shfl_xor(sq, m);
    sk += __shfl_xor(sk, m);
  }
  float rq = rsqrt_nr(sq + EPSc) * SCALEc;
  float rk = rsqrt_nr(sk + EPSc);
  size_t orow = ((size_t)(b * Hc + h) * Tc + t) * Kc;
  ((float2*)(qh + orow))[lane] = make_float2(vq.x * rq, vq.y * rq);
  ((float2*)(kh + orow))[lane] = make_float2(vk.x * rk, vk.y * rk);
}

// ---------------- Phase 1b: per-chunk inclusive cumsum of g ----------------
__global__ __launch_bounds__(256) void k_gates(const float* __restrict__ g,
                                               float* __restrict__ Gc) {
  int cid = blockIdx.x * 4 + (threadIdx.x >> 6);  // bh*NC + c
  int lane = threadIdx.x & 63;
  int bh = cid >> 5, c = cid & 31;
  int b = bh >> 4, h = bh & 15;
  int t = c * CHUNK + lane;
  float val = g[((size_t)(b * Tc + t)) * Hc + h];
#pragma unroll
  for (int d = 1; d < 64; d <<= 1) {
    float u = __shfl_up(val, d);
    if (lane >= d) val += u;
  }
  Gc[(size_t)bh * Tc + t] = val;
}

// ---------------- Phase 1c: Att[i][j] = exp(Gi-Gj)*(qi.kj), j<=i -----------
// dyn LDS: k_lds[64][132], q_lds[64][132], eG[64], enG[64]  = 68096 B
__global__ __launch_bounds__(256) void k3_att(const float* __restrict__ qh,
                                              const float* __restrict__ kh,
                                              const float* __restrict__ Gc,
                                              float* __restrict__ Am) {
  extern __shared__ float smem_a[];
  float* k_lds = smem_a;            // stride 132
  float* q_lds = k_lds + 64 * 132;
  float* eG = q_lds + 64 * 132;
  float* enG = eG + 64;
  int cid = blockIdx.x;
  int bh = cid >> 5, c = cid & 31;
  int tid = threadIdx.x;
  const float4* kg = (const float4*)(kh + ((size_t)bh * Tc + c * CHUNK) * Kc);
  const float4* qg = (const float4*)(qh + ((size_t)bh * Tc + c * CHUNK) * Kc);
#pragma unroll
  for (int r = 0; r < 8; ++r) {
    int f = tid + r * 256;
    int row = f >> 5, c4 = f & 31;
    *(float4*)&k_lds[row * 132 + c4 * 4] = kg[f];
    *(float4*)&q_lds[row * 132 + c4 * 4] = qg[f];
  }
  if (tid < 64) {
    float gv = Gc[(size_t)bh * Tc + c * CHUNK + tid];
    eG[tid] = expf(gv);
    enG[tid] = expf(-gv);
  }
  __syncthreads();
  int tx = tid & 15, ty = tid >> 4;
  float acc[4][4];
#pragma unroll
  for (int a = 0; a < 4; ++a)
#pragma unroll
    for (int b2 = 0; b2 < 4; ++b2) acc[a][b2] = 0.f;
#pragma unroll 4
  for (int c4 = 0; c4 < 32; ++c4) {
    float4 qf[4], kf[4];
#pragma unroll
    for (int ii = 0; ii < 4; ++ii) qf[ii] = *(const float4*)&q_lds[(ty + 16 * ii) * 132 + c4 * 4];
#pragma unroll
    for (int jj = 0; jj < 4; ++jj) kf[jj] = *(const float4*)&k_lds[(tx + 16 * jj) * 132 + c4 * 4];
#pragma unroll
    for (int ii = 0; ii < 4; ++ii)
#pragma unroll
      for (int jj = 0; jj < 4; ++jj) {
        acc[ii][jj] = fmaf(qf[ii].x, kf[jj].x, acc[ii][jj]);
        acc[ii][jj] = fmaf(qf[ii].y, kf[jj].y, acc[ii][jj]);
        acc[ii][jj] = fmaf(qf[ii].z, kf[jj].z, acc[ii][jj]);
        acc[ii][jj] = fmaf(qf[ii].w, kf[jj].w, acc[ii][jj]);
      }
  }
  float* Ab = Am + (size_t)cid * 4096;
#pragma unroll
  for (int ii = 0; ii < 4; ++ii) {
    int i = ty + 16 * ii;
#pragma unroll
    for (int jj = 0; jj < 4; ++jj) {
      int j = tx + 16 * jj;
      float dec = eG[i] * enG[j];
      Ab[i * 64 + j] = (j <= i) ? acc[ii][jj] * dec : 0.f;
    }
  }
}

// ---------------- Phase 1d: T = (I + W)^{-1}  ------------------------------
// dyn LDS: k_lds[64][132], A[64][65], eG, enG, bet = 51200 B
__global__ __launch_bounds__(256) void k3_tmat(const float* __restrict__ kh,
                                               const float* __restrict__ Gc,
                                               const float* __restrict__ beta,
                                               float* __restrict__ Tm) {
  extern __shared__ float smem_b[];
  float* k_lds = smem_b;             // stride 132
  float* A = k_lds + 64 * 132;       // [64][65]
  float* eG = A + 64 * 65;
  float* enG = eG + 64;
  float* bet = enG + 64;
  int cid = blockIdx.x;
  int bh = cid >> 5, c = cid & 31;
  int b = bh >> 4, h = bh & 15;
  int tid = threadIdx.x;
  const float4* kg = (const float4*)(kh + ((size_t)bh * Tc + c * CHUNK) * Kc);
#pragma unroll
  for (int r = 0; r < 8; ++r) {
    int f = tid + r * 256;
    int row = f >> 5, c4 = f & 31;
    *(float4*)&k_lds[row * 132 + c4 * 4] = kg[f];
  }
  if (tid < 64) {
    float gv = Gc[(size_t)bh * Tc + c * CHUNK + tid];
    eG[tid] = expf(gv);
    enG[tid] = expf(-gv);
    bet[tid] = beta[((size_t)(b * Tc + c * CHUNK + tid)) * Hc + h];
  }
  __syncthreads();
  int tx = tid & 15, ty = tid >> 4;
  float acc[4][4];
#pragma unroll
  for (int a = 0; a < 4; ++a)
#pragma unroll
    for (int b2 = 0; b2 < 4; ++b2) acc[a][b2] = 0.f;
#pragma unroll 4
  for (int c4 = 0; c4 < 32; ++c4) {
    float4 rf[4], cf[4];
#pragma unroll
    for (int ii = 0; ii < 4; ++ii) rf[ii] = *(const float4*)&k_lds[(ty + 16 * ii) * 132 + c4 * 4];
#pragma unroll
    for (int jj = 0; jj < 4; ++jj) cf[jj] = *(const float4*)&k_lds[(tx + 16 * jj) * 132 + c4 * 4];
#pragma unroll
    for (int ii = 0; ii < 4; ++ii)
#pragma unroll
      for (int jj = 0; jj < 4; ++jj) {
        acc[ii][jj] = fmaf(rf[ii].x, cf[jj].x, acc[ii][jj]);
        acc[ii][jj] = fmaf(rf[ii].y, cf[jj].y, acc[ii][jj]);
        acc[ii][jj] = fmaf(rf[ii].z, cf[jj].z, acc[ii][jj]);
        acc[ii][jj] = fmaf(rf[ii].w, cf[jj].w, acc[ii][jj]);
      }
  }
  // A = -W (strict lower), 0 elsewhere
#pragma unroll
  for (int ii = 0; ii < 4; ++ii) {
    int i = ty + 16 * ii;
#pragma unroll
    for (int jj = 0; jj < 4; ++jj) {
      int j = tx + 16 * jj;
      float w = bet[i] * (eG[i] * enG[j]) * acc[ii][jj];
      A[i * 65 + j] = (j < i) ? -w : 0.f;
    }
  }
  __syncthreads();
  // in-place row sweep: X = -W - W X  (row i uses orig row i of -W and
  // updated rows s<i). One wave; rotate which wave per block to spread SIMDs.
  int wid = tid >> 6;
  int wsel = blockIdx.x & 3;
  if (wid == wsel) {
    int lane = tid & 63;
    for (int i = 2; i < 64; ++i) {
      float val = A[i * 65 + lane];
      for (int s = 1; s < i; ++s) {
        float ais = A[i * 65 + s];       // original -W[i][s] (row i untouched)
        float asj = A[s * 65 + lane];    // updated X[s][j]
        val = (lane < s) ? fmaf(ais, asj, val) : val;
      }
      if (lane < i) A[i * 65 + lane] = val;
    }
  }
  __syncthreads();
  float* Tb = Tm + (size_t)cid * 4096;
#pragma unroll
  for (int r = 0; r < 16; ++r) {
    int f = tid + r * 256;
    int row = f >> 6, col = f & 63;
    float v = (col < row) ? A[row * 65 + col] : ((col == row) ? 1.f : 0.f);
    Tb[f] = v;
  }
}

// ---------------- Phase 2: chunk-serial scan -------------------------------
// grid 256 = (bh, vb): 32 V-cols per block; 256 threads (4 waves).
// dyn LDS: k[64][128] swz, q[64][128] swz, T[64][68], Att[64][68],
//          P[64][36], B[64][36], U[64][36], eG,enG,bet  = 128768 B
__global__ __launch_bounds__(256) void gdn_p2(
    const float* __restrict__ qh, const float* __restrict__ kh,
    const float* __restrict__ Tm, const float* __restrict__ Am,
    const float* __restrict__ Gc, const float* __restrict__ v,
    const float* __restrict__ beta, const float* __restrict__ s0,
    float* __restrict__ o, float* __restrict__ fs) {
  extern __shared__ float smem[];
  float* k_lds = smem;               // [64][128] swizzled
  float* q_lds = k_lds + 64 * 128;
  float* T_lds = q_lds + 64 * 128;   // [64][68]
  float* A_lds = T_lds + 64 * 68;    // [64][68]
  float* P_lds = A_lds + 64 * 68;    // [64][36]  (also OI)
  float* B_lds = P_lds + 64 * 36;
  float* U_lds = B_lds + 64 * 36;
  float* eG = U_lds + 64 * 36;
  float* enG = eG + 64;
  float* bet = enG + 64;

  int bid = blockIdx.x;
  int vb = bid & 3;
  int bh = bid >> 2;
  int b = bh >> 4, h = bh & 15;
  int tid = threadIdx.x;
  int tk = tid & 7, tv = tid >> 3;
  int k0 = tk * 16;
  int vcol = vb * 32 + tv;
  int i4 = tid >> 2;            // row for B/U/O mapping
  int vg8 = (tid & 3) * 8;      // local col offset

  // state S[k0+j][vcol]
  float S[16];
  {
    const float* s0p = s0 + ((size_t)bh * Kc + k0) * Vc + vcol;
#pragma unroll
    for (int j = 0; j < 16; ++j) S[j] = s0p[(size_t)j * Vc];
  }
  // swizzled float offsets of this thread's 4 row-frags
  int pofs[4];
#pragma unroll
  for (int m = 0; m < 4; ++m) pofs[m] = swz5(4 * tk + m) * 4;

  const float* kh_b = kh + (size_t)bh * Tc * Kc;
  const float* qh_b = qh + (size_t)bh * Tc * Kc;
  const float* Tm_b = Tm + (size_t)bh * NCc * 4096;
  const float* Am_b = Am + (size_t)bh * NCc * 4096;

  for (int c = 0; c < NCc; ++c) {
    __syncthreads();  // protect LDS from previous iteration readers

    // v prefetch for (b)
    const float* vrow = v + (((size_t)(b * Tc + c * CHUNK + i4)) * Hc + h) * Vc + vb * 32 + vg8;
    float4 vp0 = ((const float4*)vrow)[0];
    float4 vp1 = ((const float4*)vrow)[1];

    // stage k,q (swizzled) and T,Att (padded 68)
    {
      const float4* kg = (const float4*)(kh_b + (size_t)c * CHUNK * Kc);
      const float4* qg = (const float4*)(qh_b + (size_t)c * CHUNK * Kc);
#pragma unroll
      for (int r = 0; r < 8; ++r) {
        int f = tid + r * 256;
        int row = f >> 5, c4 = f & 31;
        int off = row * 128 + swz5(c4) * 4;
        *(float4*)&k_lds[off] = kg[f];
        *(float4*)&q_lds[off] = qg[f];
      }
      const float4* tg = (const float4*)(Tm_b + (size_t)c * 4096);
      const float4* ag = (const float4*)(Am_b + (size_t)c * 4096);
#pragma unroll
      for (int r = 0; r < 4; ++r) {
        int f = tid + r * 256;
        int row = f >> 4, c4 = f & 15;
        *(float4*)&T_lds[row * 68 + c4 * 4] = tg[f];
        *(float4*)&A_lds[row * 68 + c4 * 4] = ag[f];
      }
      if (tid < 64) {
        float gv = Gc[(size_t)bh * Tc + c * CHUNK + tid];
        eG[tid] = expf(gv);
        enG[tid] = expf(-gv);
        bet[tid] = beta[((size_t)(b * Tc + c * CHUNK + tid)) * Hc + h];
      }
    }
    __syncthreads();  // s1

    // (a) P = Kchunk @ S0
#pragma unroll 2
    for (int i = 0; i < 64; ++i) {
      const float* kr = &k_lds[i * 128];
      float4 f0 = *(const float4*)(kr + pofs[0]);
      float4 f1 = *(const float4*)(kr + pofs[1]);
      float4 f2 = *(const float4*)(kr + pofs[2]);
      float4 f3 = *(const float4*)(kr + pofs[3]);
      float p0 = fmaf(f0.x, S[0], fmaf(f0.y, S[1], fmaf(f0.z, S[2], f0.w * S[3])));
      float p1 = fmaf(f1.x, S[4], fmaf(f1.y, S[5], fmaf(f1.z, S[6], f1.w * S[7])));
      float p2 = fmaf(f2.x, S[8], fmaf(f2.y, S[9], fmaf(f2.z, S[10], f2.w * S[11])));
      float p3 = fmaf(f3.x, S[12], fmaf(f3.y, S[13], fmaf(f3.z, S[14], f3.w * S[15])));
      float val = (p0 + p1) + (p2 + p3);
      val += __shfl_xor(val, 1);
      val += __shfl_xor(val, 2);
      val += __shfl_xor(val, 4);
      if (tk == 0) P_lds[i * 36 + tv] = val;
    }
    __syncthreads();  // s2

    // (b) B = beta*(v - eG*P)
    {
      float4 P0 = *(const float4*)&P_lds[i4 * 36 + vg8];
      float4 P1 = *(const float4*)&P_lds[i4 * 36 + vg8 + 4];
      float bi = bet[i4], Ai = eG[i4];
      float4 B0, B1;
      B0.x = bi * (vp0.x - Ai * P0.x); B0.y = bi * (vp0.y - Ai * P0.y);
      B0.z = bi * (vp0.z - Ai * P0.z); B0.w = bi * (vp0.w - Ai * P0.w);
      B1.x = bi * (vp1.x - Ai * P1.x); B1.y = bi * (vp1.y - Ai * P1.y);
      B1.z = bi * (vp1.z - Ai * P1.z); B1.w = bi * (vp1.w - Ai * P1.w);
      *(float4*)&B_lds[i4 * 36 + vg8] = B0;
      *(float4*)&B_lds[i4 * 36 + vg8 + 4] = B1;
    }
    __syncthreads();  // s3

    // (c) U = T @ B
    {
      float acc[8];
#pragma unroll
      for (int m = 0; m < 8; ++m) acc[m] = 0.f;
#pragma unroll 4
      for (int s = 0; s < 64; ++s) {
        float t_is = T_lds[i4 * 68 + s];
        float4 b0 = *(const float4*)&B_lds[s * 36 + vg8];
        float4 b1 = *(const float4*)&B_lds[s * 36 + vg8 + 4];
        acc[0] = fmaf(t_is, b0.x, acc[0]); acc[1] = fmaf(t_is, b0.y, acc[1]);
        acc[2] = fmaf(t_is, b0.z, acc[2]); acc[3] = fmaf(t_is, b0.w, acc[3]);
        acc[4] = fmaf(t_is, b1.x, acc[4]); acc[5] = fmaf(t_is, b1.y, acc[5]);
        acc[6] = fmaf(t_is, b1.z, acc[6]); acc[7] = fmaf(t_is, b1.w, acc[7]);
      }
      *(float4*)&U_lds[i4 * 36 + vg8] = make_float4(acc[0], acc[1], acc[2], acc[3]);
      *(float4*)&U_lds[i4 * 36 + vg8 + 4] = make_float4(acc[4], acc[5], acc[6], acc[7]);
    }
    __syncthreads();  // s4

    // (e) OI = Qchunk @ S0 (raw; eG applied at combine) -> reuse P_lds
#pragma unroll 2
    for (int i = 0; i < 64; ++i) {
      const float* qr = &q_lds[i * 128];
      float4 f0 = *(const float4*)(qr + pofs[0]);
      float4 f1 = *(const float4*)(qr + pofs[1]);
      float4 f2 = *(const float4*)(qr + pofs[2]);
      float4 f3 = *(const float4*)(qr + pofs[3]);
      float p0 = fmaf(f0.x, S[0], fmaf(f0.y, S[1], fmaf(f0.z, S[2], f0.w * S[3])));
      float p1 = fmaf(f1.x, S[4], fmaf(f1.y, S[5], fmaf(f1.z, S[6], f1.w * S[7])));
      float p2 = fmaf(f2.x, S[8], fmaf(f2.y, S[9], fmaf(f2.z, S[10], f2.w * S[11])));
      float p3 = fmaf(f3.x, S[12], fmaf(f3.y, S[13], fmaf(f3.z, S[14], f3.w * S[15])));
      float val = (p0 + p1) + (p2 + p3);
      val += __shfl_xor(val, 1);
      val += __shfl_xor(val, 2);
      val += __shfl_xor(val, 4);
      if (tk == 0) P_lds[i * 36 + tv] = val;
    }

    // (f) S = Aend*S + sum_s (Aend*enG[s]) * U[s][tv] * k_s
    {
      float Aend = eG[63];
#pragma unroll
      for (int j = 0; j < 16; ++j) S[j] *= Aend;
#pragma unroll 2
      for (int s = 0; s < 64; ++s) {
        float u = U_lds[s * 36 + tv];
        float cc = u * (Aend * enG[s]);
        const float* kr = &k_lds[s * 128];
        float4 f0 = *(const float4*)(kr + pofs[0]);
        float4 f1 = *(const float4*)(kr + pofs[1]);
        float4 f2 = *(const float4*)(kr + pofs[2]);
        float4 f3 = *(const float4*)(kr + pofs[3]);
        S[0] = fmaf(cc, f0.x, S[0]);  S[1] = fmaf(cc, f0.y, S[1]);
        S[2] = fmaf(cc, f0.z, S[2]);  S[3] = fmaf(cc, f0.w, S[3]);
        S[4] = fmaf(cc, f1.x, S[4]);  S[5] = fmaf(cc, f1.y, S[5]);
        S[6] = fmaf(cc, f1.z, S[6]);  S[7] = fmaf(cc, f1.w, S[7]);
        S[8] = fmaf(cc, f2.x, S[8]);  S[9] = fmaf(cc, f2.y, S[9]);
        S[10] = fmaf(cc, f2.z, S[10]); S[11] = fmaf(cc, f2.w, S[11]);
        S[12] = fmaf(cc, f3.x, S[12]); S[13] = fmaf(cc, f3.y, S[13]);
        S[14] = fmaf(cc, f3.z, S[14]); S[15] = fmaf(cc, f3.w, S[15]);
      }
    }
    __syncthreads();  // s5

    // (d+g) o = eG[i]*OI + Att @ U, write global
    {
      float acc[8];
#pragma unroll
      for (int m = 0; m < 8; ++m) acc[m] = 0.f;
#pragma unroll 4
      for (int s = 0; s < 64; ++s) {
        float a_is = A_lds[i4 * 68 + s];
        float4 u0 = *(const float4*)&U_lds[s * 36 + vg8];
        float4 u1 = *(const float4*)&U_lds[s * 36 + vg8 + 4];
        acc[0] = fmaf(a_is, u0.x, acc[0]); acc[1] = fmaf(a_is, u0.y, acc[1]);
        acc[2] = fmaf(a_is, u0.z, acc[2]); acc[3] = fmaf(a_is, u0.w, acc[3]);
        acc[4] = fmaf(a_is, u1.x, acc[4]); acc[5] = fmaf(a_is, u1.y, acc[5]);
        acc[6] = fmaf(a_is, u1.z, acc[6]); acc[7] = fmaf(a_is, u1.w, acc[7]);
      }
      float4 oi0 = *(const float4*)&P_lds[i4 * 36 + vg8];
      float4 oi1 = *(const float4*)&P_lds[i4 * 36 + vg8 + 4];
      float Ai = eG[i4];
      float4 o0, o1;
      o0.x = fmaf(Ai, oi0.x, acc[0]); o0.y = fmaf(Ai, oi0.y, acc[1]);
      o0.z = fmaf(Ai, oi0.z, acc[2]); o0.w = fmaf(Ai, oi0.w, acc[3]);
      o1.x = fmaf(Ai, oi1.x, acc[4]); o1.y = fmaf(Ai, oi1.y, acc[5]);
      o1.z = fmaf(Ai, oi1.z, acc[6]); o1.w = fmaf(Ai, oi1.w, acc[7]);
      float* orow = o + (((size_t)(b * Tc + c * CHUNK + i4)) * Hc + h) * Vc + vb * 32 + vg8;
      ((float4*)orow)[0] = o0;
      ((float4*)orow)[1] = o1;
    }
  }

  // final state
  float* fsp = fs + ((size_t)bh * Kc + k0) * Vc + vcol;
#pragma unroll
  for (int j = 0; j < 16; ++j) fsp[(size_t)j * Vc] = S[j];
}

// =================== Legacy fallback (proven correct) ======================
__global__ __launch_bounds__(256) void norm_qk(const float* __restrict__ q,
                                               const float* __restrict__ k,
                                               float* __restrict__ qn,
                                               float* __restrict__ kn) {
  int gtid = blockIdx.x * 256 + threadIdx.x;
  int row = gtid >> 6;
  int lane = gtid & 63;
  const float2 vq = ((const float2*)(q + (size_t)row * Kc))[lane];
  const float2 vk = ((const float2*)(k + (size_t)row * Kc))[lane];
  float sq = vq.x * vq.x + vq.y * vq.y;
  float sk = vk.x * vk.x + vk.y * vk.y;
#pragma unroll
  for (int m = 1; m < 64; m <<= 1) {
    sq += __shfl_xor(sq, m);
    sk += __shfl_xor(sk, m);
  }
  float rq = rsqrt_nr(sq + EPSc) * SCALEc;
  float rk = rsqrt_nr(sk + EPSc);
  ((float2*)(qn + (size_t)row * Kc))[lane] = make_float2(vq.x * rq, vq.y * rq);
  ((float2*)(kn + (size_t)row * Kc))[lane] = make_float2(vk.x * rk, vk.y * rk);
}

template <bool PRENORM>
__global__ __launch_bounds__(256) void gdn_scan(
    const float* __restrict__ q, const float* __restrict__ k,
    const float* __restrict__ v, const float* __restrict__ g,
    const float* __restrict__ beta, const float* __restrict__ s0,
    float* __restrict__ o, float* __restrict__ fs) {
  const int bid = blockIdx.x;
  const int vb = bid & 3;
  const int bh = bid >> 2;
  const int b = bh >> 4;
  const int h = bh & 15;
  const int tid = threadIdx.x;
  const int tk = tid & 7;
  const int tv = tid >> 3;
  const int vcol = vb * 32 + tv;
  const int k0 = tk * 16;
  float S[16];
  {
    const float* s0p = s0 + ((size_t)bh * Kc + k0) * Vc + vcol;
#pragma unroll
    for (int i = 0; i < 16; ++i) S[i] = s0p[(size_t)i * Vc];
  }
  const size_t qk_base = (size_t)b * Tc * Hc * Kc + (size_t)h * Kc + k0;
  const size_t v_base = (size_t)b * Tc * Hc * Vc + (size_t)h * Vc + vcol;
  const size_t gb_base = (size_t)b * Tc * Hc + h;
  const size_t qk_stride = (size_t)Hc * Kc;
  const size_t v_stride = (size_t)Hc * Vc;
  const size_t gb_stride = (size_t)Hc;
  float4 cq[4], ck[4];
  float cv, cg, cb;
  {
    const float* qrow = q + qk_base;
    const float* krow = k + qk_base;
#pragma unroll
    for (int i = 0; i < 4; ++i) {
      cq[i] = ((const float4*)qrow)[i];
      ck[i] = ((const float4*)krow)[i];
    }
    cv = v[v_base];
    cg = g[gb_base];
    cb = beta[gb_base];
  }
  for (int t = 0; t < Tc; ++t) {
    float4 nq[4], nk[4];
    float nv, ng, nb;
    {
      int tn = (t + 1 < Tc) ? (t + 1) : t;
      const float* qrow = q + qk_base + (size_t)tn * qk_stride;
      const float* krow = k + qk_base + (size_t)tn * qk_stride;
#pragma unroll
      for (int i = 0; i < 4; ++i) {
        nq[i] = ((const float4*)qrow)[i];
        nk[i] = ((const float4*)krow)[i];
      }
      nv = v[v_base + (size_t)tn * v_stride];
      ng = g[gb_base + (size_t)tn * gb_stride];
      nb = beta[gb_base + (size_t)tn * gb_stride];
    }
    float qn_[16], kn_[16];
#pragma unroll
    for (int i = 0; i < 4; ++i) {
      qn_[4 * i + 0] = cq[i].x; qn_[4 * i + 1] = cq[i].y;
      qn_[4 * i + 2] = cq[i].z; qn_[4 * i + 3] = cq[i].w;
      kn_[4 * i + 0] = ck[i].x; kn_[4 * i + 1] = ck[i].y;
      kn_[4 * i + 2] = ck[i].z; kn_[4 * i + 3] = ck[i].w;
    }
    if (!PRENORM) {
      float sq = 0.f, sk = 0.f;
#pragma unroll
      for (int i = 0; i < 16; ++i) {
        sq = fmaf(qn_[i], qn_[i], sq);
        sk = fmaf(kn_[i], kn_[i], sk);
      }
#pragma unroll
      for (int m = 1; m < 8; m <<= 1) {
        sq += __shfl_xor(sq, m);
        sk += __shfl_xor(sk, m);
      }
      float rq = rsqrt_nr(sq + EPSc) * SCALEc;
      float rk = rsqrt_nr(sk + EPSc);
#pragma unroll
      for (int i = 0; i < 16; ++i) {
        qn_[i] *= rq;
        kn_[i] *= rk;
      }
    }
    float eg = expf(cg);
    float p0 = 0.f, p1 = 0.f, p2 = 0.f, p3 = 0.f;
#pragma unroll
    for (int i = 0; i < 16; i += 4) {
      p0 = fmaf(kn_[i + 0], S[i + 0], p0);
      p1 = fmaf(kn_[i + 1], S[i + 1], p1);
      p2 = fmaf(kn_[i + 2], S[i + 2], p2);
      p3 = fmaf(kn_[i + 3], S[i + 3], p3);
    }
    float pred = (p0 + p1) + (p2 + p3);
#pragma unroll
    for (int m = 1; m < 8; m <<= 1) pred += __shfl_xor(pred, m);
    pred *= eg;
    float vadj = (cv - pred) * cb;
#pragma unroll
    for (int i = 0; i < 16; ++i) S[i] = fmaf(S[i], eg, kn_[i] * vadj);
    float o0 = 0.f, o1 = 0.f, o2 = 0.f, o3 = 0.f;
#pragma unroll
    for (int i = 0; i < 16; i += 4) {
      o0 = fmaf(qn_[i + 0], S[i + 0], o0);
      o1 = fmaf(qn_[i + 1], S[i + 1], o1);
      o2 = fmaf(qn_[i + 2], S[i + 2], o2);
      o3 = fmaf(qn_[i + 3], S[i + 3], o3);
    }
    float out = (o0 + o1) + (o2 + o3);
#pragma unroll
    for (int m = 1; m < 8; m <<= 1) out += __shfl_xor(out, m);
    if (tk == 0) o[((size_t)(b * Tc + t) * Hc + h) * Vc + vcol] = out;
#pragma unroll
    for (int i = 0; i < 4; ++i) {
      cq[i] = nq[i];
      ck[i] = nk[i];
    }
    cv = nv;
    cg = ng;
    cb = nb;
  }
  float* fsp = fs + ((size_t)bh * Kc + k0) * Vc + vcol;
#pragma unroll
  for (int i = 0; i < 16; ++i) fsp[(size_t)i * Vc] = S[i];
}

// =========================================================================
extern "C" void kernel_launch(void* const* d_in, const int* in_sizes, int n_in,
                              void* d_out, int out_size, void* d_ws, size_t ws_size,
                              hipStream_t stream) {
  const float* q = (const float*)d_in[0];
  const float* k = (const float*)d_in[1];
  const float* v = (const float*)d_in[2];
  const float* g = (const float*)d_in[3];
  const float* beta = (const float*)d_in[4];
  const float* s0 = (const float*)d_in[5];
  float* o = (float*)d_out;
  float* fs = o + (size_t)Bc * Tc * Hc * Vc;

  const size_t QK = (size_t)Bc * Hc * Tc * Kc;       // 16777216
  const size_t BHT = (size_t)Bc * Hc * Tc;           // 131072
  const size_t TMsz = (size_t)Bc * Hc * NCc * 4096;  // 8388608
  const size_t need_chunked = (2 * QK + BHT + 2 * TMsz) * sizeof(float);  // ~192.5MB
  const size_t need_prenorm = 2 * QK * sizeof(float);

  if (ws_size >= need_chunked) {
    float* qh = (float*)d_ws;
    float* kh = qh + QK;
    float* Gc = kh + QK;
    float* Tm = Gc + BHT;
    float* Am = Tm + TMsz;

    static bool attr_done = false;
    (void)attr_done;
    hipFuncSetAttribute(reinterpret_cast<const void*>(k3_att),
                        hipFuncAttributeMaxDynamicSharedMemorySize, 68096);
    hipFuncSetAttribute(reinterpret_cast<const void*>(gdn_p2),
                        hipFuncAttributeMaxDynamicSharedMemorySize, 128768);
    hipFuncSetAttribute(reinterpret_cast<const void*>(k3_tmat),
                        hipFuncAttributeMaxDynamicSharedMemorySize, 51200);

    norm_qk_t<<<(Bc * Tc * Hc) / 4, 256, 0, stream>>>(q, k, qh, kh);
    k_gates<<<(Bc * Hc * NCc) / 4, 256, 0, stream>>>(g, Gc);
    k3_att<<<Bc * Hc * NCc, 256, 68096, stream>>>(qh, kh, Gc, Am);
    k3_tmat<<<Bc * Hc * NCc, 256, 51200, stream>>>(kh, Gc, beta, Tm);
    gdn_p2<<<Bc * Hc * 4, 256, 128768, stream>>>(qh, kh, Tm, Am, Gc, v, beta, s0, o, fs);
  } else if (ws_size >= need_prenorm) {
    float* qn = (float*)d_ws;
    float* kn = qn + QK;
    norm_qk<<<(Bc * Tc * Hc) / 4, 256, 0, stream>>>(q, k, qn, kn);
    gdn_scan<true><<<Bc * Hc * 4, 256, 0, stream>>>(qn, kn, v, g, beta, s0, o, fs);
  } else {
    gdn_scan<false><<<Bc * Hc * 4, 256, 0, stream>>>(q, k, v, g, beta, s0, o, fs);
  }
}

// Round 3
// 875.244 us; speedup vs baseline: 2.4131x; 2.4131x over previous
//
#include <hip/hip_runtime.h>

// Problem constants: B=4, T=2048, H=16, K=128, V=128
constexpr int Bc = 4, Tc = 2048, Hc = 16, Kc = 128, Vc = 128;
constexpr int CHUNK = 64, NCc = Tc / CHUNK;  // 32 chunks
constexpr float EPSc = 1e-6f;
constexpr float SCALEc = 0.08838834764831845f; // 128^-0.5

typedef float f32x4 __attribute__((ext_vector_type(4)));
typedef short s16x8 __attribute__((ext_vector_type(8)));

#define MFMA_BF16(a, b, c) __builtin_amdgcn_mfma_f32_16x16x32_bf16(a, b, c, 0, 0, 0)

__device__ __forceinline__ float rsqrt_nr(float s) {
  float r = rsqrtf(s);
  r = r * (1.5f - 0.5f * s * r * r);
  return r;
}

__device__ __forceinline__ unsigned short f2bf(float x) {
  unsigned int u = __builtin_bit_cast(unsigned int, x);
  unsigned int r = u + 0x7fffu + ((u >> 16) & 1u);
  return (unsigned short)(r >> 16);
}
__device__ __forceinline__ float bf2f(unsigned short u) {
  unsigned int w = ((unsigned int)u) << 16;
  return __builtin_bit_cast(float, w);
}
__device__ __forceinline__ s16x8 bc16(uint4 u) { return __builtin_bit_cast(s16x8, u); }

// split 8 consecutive f32 (from LDS) into hi/lo bf16 fragments
__device__ __forceinline__ void splitfrag(const float* p, s16x8& hi, s16x8& lo) {
  f32x4 a = *(const f32x4*)p;
  f32x4 b = *(const f32x4*)(p + 4);
  float x[8] = {a[0], a[1], a[2], a[3], b[0], b[1], b[2], b[3]};
  s16x8 h, l;
#pragma unroll
  for (int j = 0; j < 8; ++j) {
    unsigned short hb = f2bf(x[j]);
    h[j] = (short)hb;
    l[j] = (short)f2bf(x[j] - bf2f(hb));
  }
  hi = h;
  lo = l;
}
__device__ __forceinline__ s16x8 cvt8(f32x4 a, f32x4 b) {
  s16x8 r;
#pragma unroll
  for (int j = 0; j < 4; ++j) {
    r[j] = (short)f2bf(a[j]);
    r[j + 4] = (short)f2bf(b[j]);
  }
  return r;
}

// ---------------- Phase 1a: normalize q,k; emit bf16 hi/lo planes [bh][t][k]
__global__ __launch_bounds__(256) void norm_planes(const float* __restrict__ q,
                                                   const float* __restrict__ k,
                                                   unsigned int* __restrict__ qhi,
                                                   unsigned int* __restrict__ qlo,
                                                   unsigned int* __restrict__ khi,
                                                   unsigned int* __restrict__ klo) {
  int row = blockIdx.x * 4 + (threadIdx.x >> 6);  // (b*T+t)*H+h
  int lane = threadIdx.x & 63;
  int b = row >> 15;
  int rem = row & 32767;
  int t = rem >> 4;
  int h = rem & 15;
  const float2 vq = ((const float2*)(q + (size_t)row * Kc))[lane];
  const float2 vk = ((const float2*)(k + (size_t)row * Kc))[lane];
  float sq = vq.x * vq.x + vq.y * vq.y;
  float sk = vk.x * vk.x + vk.y * vk.y;
#pragma unroll
  for (int m = 1; m < 64; m <<= 1) {
    sq += __shfl_xor(sq, m);
    sk += __shfl_xor(sk, m);
  }
  float rq = rsqrt_nr(sq + EPSc) * SCALEc;
  float rk = rsqrt_nr(sk + EPSc);
  float x0 = vq.x * rq, x1 = vq.y * rq;
  float y0 = vk.x * rk, y1 = vk.y * rk;
  unsigned short qh0 = f2bf(x0), qh1 = f2bf(x1);
  unsigned short kh0 = f2bf(y0), kh1 = f2bf(y1);
  unsigned short ql0 = f2bf(x0 - bf2f(qh0)), ql1 = f2bf(x1 - bf2f(qh1));
  unsigned short kl0 = f2bf(y0 - bf2f(kh0)), kl1 = f2bf(y1 - bf2f(kh1));
  size_t o32 = ((size_t)(b * Hc + h) * Tc + t) * 64 + lane;  // u32 units
  qhi[o32] = (unsigned int)qh0 | ((unsigned int)qh1 << 16);
  qlo[o32] = (unsigned int)ql0 | ((unsigned int)ql1 << 16);
  khi[o32] = (unsigned int)kh0 | ((unsigned int)kh1 << 16);
  klo[o32] = (unsigned int)kl0 | ((unsigned int)kl1 << 16);
}

// ---------------- Phase 1b: per-chunk inclusive cumsum of g ----------------
__global__ __launch_bounds__(256) void k_gates(const float* __restrict__ g,
                                               float* __restrict__ Gc) {
  int cid = blockIdx.x * 4 + (threadIdx.x >> 6);
  int lane = threadIdx.x & 63;
  int bh = cid >> 5, c = cid & 31;
  int b = bh >> 4, h = bh & 15;
  int t = c * CHUNK + lane;
  float val = g[((size_t)(b * Tc + t)) * Hc + h];
#pragma unroll
  for (int d = 1; d < 64; d <<= 1) {
    float u = __shfl_up(val, d);
    if (lane >= d) val += u;
  }
  Gc[(size_t)bh * Tc + t] = val;
}

// ---------------- Phase 1d: T = (I + W)^{-1} via MFMA W + serial sweep -----
// dyn LDS: Khi[64][136]sh, Klo[64][136]sh, A[64][65]f32, eG/enG/bet = 52224 B
__global__ __launch_bounds__(256) void k_tmat(const unsigned short* __restrict__ khi_g,
                                              const unsigned short* __restrict__ klo_g,
                                              const float* __restrict__ Gc,
                                              const float* __restrict__ beta_g,
                                              unsigned int* __restrict__ Tm32) {
  extern __shared__ char smemb[];
  unsigned short* Khi = (unsigned short*)smemb;          // 8704
  unsigned short* Klo = Khi + 8704;                      // 8704
  float* A = (float*)(Klo + 8704);                       // 4160 f32
  float* eG = A + 64 * 65;
  float* enG = eG + 64;
  float* bet = enG + 64;

  int cid = blockIdx.x;
  int bh = cid >> 5, c = cid & 31;
  int b = bh >> 4, h = bh & 15;
  int tid = threadIdx.x;
  int lane = tid & 63, w = tid >> 6;
  int wm = w & 1, wn = w >> 1;
  int l15 = lane & 15, g4 = lane >> 4;

#pragma unroll
  for (int r2 = 0; r2 < 4; ++r2) {
    int f = tid + 256 * r2;
    int s = f >> 4, cc = f & 15;
    size_t gsrc = ((size_t)bh * Tc + c * CHUNK + s) * Kc + cc * 8;
    *(uint4*)&Khi[s * 136 + cc * 8] = *(const uint4*)(khi_g + gsrc);
    *(uint4*)&Klo[s * 136 + cc * 8] = *(const uint4*)(klo_g + gsrc);
  }
  if (tid < 64) {
    float gv = Gc[(size_t)bh * Tc + c * CHUNK + tid];
    eG[tid] = expf(gv);
    enG[tid] = expf(-gv);
    bet[tid] = beta_g[((size_t)(b * Tc + c * CHUNK + tid)) * Hc + h];
  }
  __syncthreads();

  // W-mm: M[i][j] = sum_kd K[i][kd]*K[j][kd], 3-term hi/lo
  f32x4 acc[2][2];
#pragma unroll
  for (int mi = 0; mi < 2; ++mi)
#pragma unroll
    for (int ni = 0; ni < 2; ++ni) acc[mi][ni] = (f32x4)0.f;
#pragma unroll
  for (int ks = 0; ks < 4; ++ks) {
    s16x8 ah[2], al[2], bh2[2], bl[2];
#pragma unroll
    for (int mi = 0; mi < 2; ++mi) {
      int rr = (l15 + 16 * (2 * wm + mi)) * 136 + 8 * g4 + 32 * ks;
      ah[mi] = bc16(*(const uint4*)&Khi[rr]);
      al[mi] = bc16(*(const uint4*)&Klo[rr]);
    }
#pragma unroll
    for (int ni = 0; ni < 2; ++ni) {
      int rr = (l15 + 16 * (2 * wn + ni)) * 136 + 8 * g4 + 32 * ks;
      bh2[ni] = bc16(*(const uint4*)&Khi[rr]);
      bl[ni] = bc16(*(const uint4*)&Klo[rr]);
    }
#pragma unroll
    for (int mi = 0; mi < 2; ++mi)
#pragma unroll
      for (int ni = 0; ni < 2; ++ni) {
        acc[mi][ni] = MFMA_BF16(ah[mi], bh2[ni], acc[mi][ni]);
        acc[mi][ni] = MFMA_BF16(al[mi], bh2[ni], acc[mi][ni]);
        acc[mi][ni] = MFMA_BF16(ah[mi], bl[ni], acc[mi][ni]);
      }
  }
#pragma unroll
  for (int mi = 0; mi < 2; ++mi)
#pragma unroll
    for (int ni = 0; ni < 2; ++ni) {
      int j = l15 + 16 * (2 * wn + ni);
#pragma unroll
      for (int r = 0; r < 4; ++r) {
        int i = 4 * g4 + r + 16 * (2 * wm + mi);
        float ww = bet[i] * eG[i] * enG[j] * acc[mi][ni][r];
        A[i * 65 + j] = (j < i) ? -ww : 0.f;
      }
    }
  __syncthreads();

  // serial sweep: X = -W - W X (row i final after step i)
  int wsel = blockIdx.x & 3;
  if (w == wsel) {
    for (int i = 2; i < 64; ++i) {
      float val = A[i * 65 + lane];
      for (int s = 1; s < i; ++s) {
        float ais = A[i * 65 + s];
        float asj = A[s * 65 + lane];
        val = (lane < s) ? fmaf(ais, asj, val) : val;
      }
      if (lane < i) A[i * 65 + lane] = val;
    }
  }
  __syncthreads();

  // write T bf16 plane (row-major [s][sigma])
#pragma unroll
  for (int r2 = 0; r2 < 8; ++r2) {
    int idx2 = tid + 256 * r2;
    int row = idx2 >> 5, cp = idx2 & 31;
    int j0 = 2 * cp, j1 = 2 * cp + 1;
    float a0 = (j0 < row) ? A[row * 65 + j0] : ((j0 == row) ? 1.f : 0.f);
    float a1 = (j1 < row) ? A[row * 65 + j1] : ((j1 == row) ? 1.f : 0.f);
    Tm32[(size_t)cid * 2048 + row * 32 + cp] =
        (unsigned int)f2bf(a0) | ((unsigned int)f2bf(a1) << 16);
  }
}

// ---------------- Phase 2: chunk-serial MFMA kernel ------------------------
// grid 256 = (bh, vb): 32 V-cols/block, 4 waves. Dyn LDS = 141824 B.
__global__ __launch_bounds__(256) void gdn3(
    const unsigned short* __restrict__ qhi_g, const unsigned short* __restrict__ qlo_g,
    const unsigned short* __restrict__ khi_g, const unsigned short* __restrict__ klo_g,
    const unsigned short* __restrict__ Tm_g, const float* __restrict__ Gc,
    const float* __restrict__ v_g, const float* __restrict__ beta_g,
    const float* __restrict__ s0_g, float* __restrict__ o_g, float* __restrict__ fs_g) {
  extern __shared__ char smem[];
  float* S_T = (float*)smem;                             // [32][132] f32  16896 B
  unsigned short* Khi = (unsigned short*)(smem + 16896); // [64][136]      17408 B
  unsigned short* Klo = Khi + 8704;
  unsigned short* Qhi = Klo + 8704;
  unsigned short* Qlo = Qhi + 8704;
  unsigned short* Kt = Qlo + 8704;                       // [128][72]      18432 B
  unsigned short* Tt = Kt + 9216;                        // [64][72]        9216 B
  unsigned short* Ybf = Tt + 4608;                       // [64][72]        9216 B
  float* Bm_T = (float*)(Ybf + 4608);                    // [32][68]        8704 B
  float* U_T = Bm_T + 32 * 68;                           // [32][68]        8704 B
  float* eG = U_T + 32 * 68;                             // 64
  float* enG = eG + 64;
  float* bet = enG + 64;
  float* wfac = bet + 64;
  unsigned int* Kt32 = (unsigned int*)Kt;
  unsigned int* Y32 = (unsigned int*)Ybf;

  int bid = blockIdx.x;
  int vb = bid & 3;
  int bh = bid >> 2;
  int b = bh >> 4, h = bh & 15;
  int tid = threadIdx.x;
  int lane = tid & 63, w = tid >> 6;
  int wm = w & 1, wn = w >> 1;
  int l15 = lane & 15, g4 = lane >> 4;

  // ---- init S_T from s0: S_T[v][kd] = s0[bh][kd][vb*32+v]
#pragma unroll
  for (int r2 = 0; r2 < 4; ++r2) {
    int f = tid + 256 * r2;
    int kd = f >> 3, vq = f & 7;
    f32x4 sv = *(const f32x4*)(s0_g + ((size_t)bh * Kc + kd) * Vc + vb * 32 + vq * 4);
#pragma unroll
    for (int j = 0; j < 4; ++j) S_T[(vq * 4 + j) * 132 + kd] = sv[j];
  }

  const size_t chunk_qk_base = (size_t)bh * Tc * Kc;

  for (int c = 0; c < NCc; ++c) {
    __syncthreads();  // (a)

    // ---- stage K/Q planes (padded rows of 136 ushorts)
#pragma unroll
    for (int r2 = 0; r2 < 4; ++r2) {
      int f = tid + 256 * r2;
      int s = f >> 4, cc = f & 15;
      size_t gsrc = chunk_qk_base + (size_t)(c * CHUNK + s) * Kc + cc * 8;
      int dst = s * 136 + cc * 8;
      *(uint4*)&Khi[dst] = *(const uint4*)(khi_g + gsrc);
      *(uint4*)&Klo[dst] = *(const uint4*)(klo_g + gsrc);
      *(uint4*)&Qhi[dst] = *(const uint4*)(qhi_g + gsrc);
      *(uint4*)&Qlo[dst] = *(const uint4*)(qlo_g + gsrc);
    }
    // ---- stage T
    {
      size_t tb = ((size_t)bh * NCc + c) * 4096;
#pragma unroll
      for (int r2 = 0; r2 < 2; ++r2) {
        int f = tid + 256 * r2;
        int row = f >> 3, cc = f & 7;
        *(uint4*)&Tt[row * 72 + cc * 8] = *(const uint4*)(Tm_g + tb + row * 64 + cc * 8);
      }
    }
    // ---- gates
    if (tid < 64) {
      float gv = Gc[(size_t)bh * Tc + c * CHUNK + tid];
      eG[tid] = expf(gv);
      enG[tid] = expf(-gv);
      bet[tid] = beta_g[((size_t)(b * Tc + c * CHUNK + tid)) * Hc + h];
    }
    // ---- v prefetch for this wave's Bm tiles
    f32x4 vld[2];
#pragma unroll
    for (int ni = 0; ni < 2; ++ni) {
      int s = l15 + 16 * (2 * wn + ni);
      vld[ni] = *(const f32x4*)(v_g + (((size_t)(b * Tc + c * CHUNK + s) * Hc + h) * Vc +
                                       vb * 32 + 16 * wm + 4 * g4));
    }
    __syncthreads();  // (b)

    if (tid < 64) wfac[tid] = eG[63] * enG[tid];

    // ---- Kt transpose (pure bf16 move of Khi)
#pragma unroll
    for (int r2 = 0; r2 < 2; ++r2) {
      int u = tid + 256 * r2;
      int sp = u & 31, cc = u >> 5;
      uint4 ra = *(const uint4*)&Khi[(2 * sp) * 136 + cc * 8];
      uint4 rb = *(const uint4*)&Khi[(2 * sp + 1) * 136 + cc * 8];
      int kd0 = cc * 8;
      unsigned int aw[4] = {ra.x, ra.y, ra.z, ra.w};
      unsigned int bw[4] = {rb.x, rb.y, rb.z, rb.w};
#pragma unroll
      for (int p = 0; p < 4; ++p) {
        unsigned int w0 = (aw[p] & 0xffffu) | (bw[p] << 16);
        unsigned int w1 = (aw[p] >> 16) | (bw[p] & 0xffff0000u);
        Kt32[36 * (kd0 + 2 * p) + sp] = w0;
        Kt32[36 * (kd0 + 2 * p + 1) + sp] = w1;
      }
    }

    // ---- X-mm: M[sigma][s] = k_sigma . q_s  (hi*hi)
    f32x4 xacc[2][2];
#pragma unroll
    for (int mi = 0; mi < 2; ++mi)
#pragma unroll
      for (int ni = 0; ni < 2; ++ni) xacc[mi][ni] = (f32x4)0.f;
#pragma unroll
    for (int ks = 0; ks < 4; ++ks) {
      s16x8 af[2], bf[2];
#pragma unroll
      for (int mi = 0; mi < 2; ++mi)
        af[mi] = bc16(*(const uint4*)&Khi[(l15 + 16 * (2 * wm + mi)) * 136 + 8 * g4 + 32 * ks]);
#pragma unroll
      for (int ni = 0; ni < 2; ++ni)
        bf[ni] = bc16(*(const uint4*)&Qhi[(l15 + 16 * (2 * wn + ni)) * 136 + 8 * g4 + 32 * ks]);
#pragma unroll
      for (int mi = 0; mi < 2; ++mi)
#pragma unroll
        for (int ni = 0; ni < 2; ++ni) xacc[mi][ni] = MFMA_BF16(af[mi], bf[ni], xacc[mi][ni]);
    }
    // X epilogue: Y[s][sigma] = eG[s]*enG[sigma]*M, sigma<=s else 0 (bf16)
#pragma unroll
    for (int mi = 0; mi < 2; ++mi) {
      int sgb = 4 * g4 + 16 * (2 * wm + mi);
#pragma unroll
      for (int ni = 0; ni < 2; ++ni) {
        int s = l15 + 16 * (2 * wn + ni);
        float egs = eG[s];
        unsigned short hb[4];
#pragma unroll
        for (int r = 0; r < 4; ++r) {
          int sigma = sgb + r;
          float val = (sigma <= s) ? xacc[mi][ni][r] * egs * enG[sigma] : 0.f;
          hb[r] = f2bf(val);
        }
        int wbase = 36 * s + (sgb >> 1);
        Y32[wbase] = (unsigned int)hb[0] | ((unsigned int)hb[1] << 16);
        Y32[wbase + 1] = (unsigned int)hb[2] | ((unsigned int)hb[3] << 16);
      }
    }

    // ---- P^T-mm: P^T[v][s] = sum_kd S_T[v][kd]*K[s][kd]  (3-term)
    f32x4 pacc[2] = {(f32x4)0.f, (f32x4)0.f};
    s16x8 shi[4], slo[4];
#pragma unroll
    for (int ks = 0; ks < 4; ++ks) {
      splitfrag(&S_T[(l15 + 16 * wm) * 132 + 8 * g4 + 32 * ks], shi[ks], slo[ks]);
      s16x8 khf[2], klf[2];
#pragma unroll
      for (int ni = 0; ni < 2; ++ni) {
        int rr = (l15 + 16 * (2 * wn + ni)) * 136 + 8 * g4 + 32 * ks;
        khf[ni] = bc16(*(const uint4*)&Khi[rr]);
        klf[ni] = bc16(*(const uint4*)&Klo[rr]);
      }
#pragma unroll
      for (int ni = 0; ni < 2; ++ni) {
        pacc[ni] = MFMA_BF16(shi[ks], khf[ni], pacc[ni]);
        pacc[ni] = MFMA_BF16(slo[ks], khf[ni], pacc[ni]);
        pacc[ni] = MFMA_BF16(shi[ks], klf[ni], pacc[ni]);
      }
    }
    // Bm epilogue: Bm^T[v][s] = bet[s]*(v - eG[s]*P^T[v][s])
#pragma unroll
    for (int ni = 0; ni < 2; ++ni) {
      int s = l15 + 16 * (2 * wn + ni);
      float bs = bet[s], egs = eG[s];
#pragma unroll
      for (int r = 0; r < 4; ++r)
        Bm_T[(4 * g4 + r + 16 * wm) * 68 + s] = bs * (vld[ni][r] - egs * pacc[ni][r]);
    }

    // ---- Oq-mm: Oq^T[v][s] = sum_kd S_T[v][kd]*Q[s][kd]  (3-term, kept in regs)
    f32x4 oqacc[2] = {(f32x4)0.f, (f32x4)0.f};
#pragma unroll
    for (int ks = 0; ks < 4; ++ks) {
      s16x8 qhf[2], qlf[2];
#pragma unroll
      for (int ni = 0; ni < 2; ++ni) {
        int rr = (l15 + 16 * (2 * wn + ni)) * 136 + 8 * g4 + 32 * ks;
        qhf[ni] = bc16(*(const uint4*)&Qhi[rr]);
        qlf[ni] = bc16(*(const uint4*)&Qlo[rr]);
      }
#pragma unroll
      for (int ni = 0; ni < 2; ++ni) {
        oqacc[ni] = MFMA_BF16(shi[ks], qhf[ni], oqacc[ni]);
        oqacc[ni] = MFMA_BF16(slo[ks], qhf[ni], oqacc[ni]);
        oqacc[ni] = MFMA_BF16(shi[ks], qlf[ni], oqacc[ni]);
      }
    }
    __syncthreads();  // (c)

    // ---- U-mm: U^T[v][s] = sum_sig Bm^T[v][sig]*T[s][sig]
    f32x4 uacc[2] = {(f32x4)0.f, (f32x4)0.f};
#pragma unroll
    for (int ks = 0; ks < 2; ++ks) {
      const float* bp = &Bm_T[(l15 + 16 * wm) * 68 + 8 * g4 + 32 * ks];
      s16x8 bmf = cvt8(*(const f32x4*)bp, *(const f32x4*)(bp + 4));
#pragma unroll
      for (int ni = 0; ni < 2; ++ni) {
        s16x8 tf = bc16(*(const uint4*)&Tt[(l15 + 16 * (2 * wn + ni)) * 72 + 8 * g4 + 32 * ks]);
        uacc[ni] = MFMA_BF16(bmf, tf, uacc[ni]);
      }
    }
#pragma unroll
    for (int ni = 0; ni < 2; ++ni) {
      int s = l15 + 16 * (2 * wn + ni);
#pragma unroll
      for (int r = 0; r < 4; ++r) U_T[(4 * g4 + r + 16 * wm) * 68 + s] = uacc[ni][r];
    }
    __syncthreads();  // (d)

    // ---- region C: Oatt + O store, then dS accumulation into S_T
    float Aend = eG[63];
    s16x8 ua[2], uw[2];
#pragma unroll
    for (int ks = 0; ks < 2; ++ks) {
      const float* up = &U_T[(l15 + 16 * wm) * 68 + 8 * g4 + 32 * ks];
      f32x4 u0 = *(const f32x4*)up, u1 = *(const f32x4*)(up + 4);
      f32x4 w0 = *(const f32x4*)&wfac[8 * g4 + 32 * ks];
      f32x4 w1 = *(const f32x4*)&wfac[8 * g4 + 32 * ks + 4];
      ua[ks] = cvt8(u0, u1);
      uw[ks] = cvt8(u0 * w0, u1 * w1);
    }
#pragma unroll
    for (int ni = 0; ni < 2; ++ni) {
      int s = l15 + 16 * (2 * wn + ni);
      float egs = eG[s];
      f32x4 oacc = oqacc[ni] * egs;
#pragma unroll
      for (int ks = 0; ks < 2; ++ks) {
        s16x8 yf = bc16(*(const uint4*)&Ybf[s * 72 + 8 * g4 + 32 * ks]);
        oacc = MFMA_BF16(ua[ks], yf, oacc);
      }
      *(f32x4*)(o_g + (((size_t)(b * Tc + c * CHUNK + s) * Hc + h) * Vc + vb * 32 +
                       16 * wm + 4 * g4)) = oacc;
    }
    // dS^T: S_T = Aend*S_T + sum_s U^T[v][s]*wfac[s]*K[s][kd]
#pragma unroll
    for (int nt = 0; nt < 4; ++nt) {
      int kd = l15 + 16 * (4 * wn + nt);
      f32x4 cin;
#pragma unroll
      for (int r = 0; r < 4; ++r) cin[r] = S_T[(4 * g4 + r + 16 * wm) * 132 + kd] * Aend;
#pragma unroll
      for (int ks = 0; ks < 2; ++ks) {
        s16x8 ktf = bc16(*(const uint4*)&Kt[kd * 72 + 8 * g4 + 32 * ks]);
        cin = MFMA_BF16(uw[ks], ktf, cin);
      }
#pragma unroll
      for (int r = 0; r < 4; ++r) S_T[(4 * g4 + r + 16 * wm) * 132 + kd] = cin[r];
    }
  }

  __syncthreads();
  // ---- final state: fs[bh][kd][vb*32+v] = S_T[v][kd]
#pragma unroll
  for (int r2 = 0; r2 < 4; ++r2) {
    int f = tid + 256 * r2;
    int kd = f >> 3, vq = f & 7;
    f32x4 sv;
#pragma unroll
    for (int j = 0; j < 4; ++j) sv[j] = S_T[(vq * 4 + j) * 132 + kd];
    *(f32x4*)(fs_g + ((size_t)bh * Kc + kd) * Vc + vb * 32 + vq * 4) = sv;
  }
}

// =================== Legacy fallback (proven correct) ======================
__global__ __launch_bounds__(256) void norm_qk(const float* __restrict__ q,
                                               const float* __restrict__ k,
                                               float* __restrict__ qn,
                                               float* __restrict__ kn) {
  int gtid = blockIdx.x * 256 + threadIdx.x;
  int row = gtid >> 6;
  int lane = gtid & 63;
  const float2 vq = ((const float2*)(q + (size_t)row * Kc))[lane];
  const float2 vk = ((const float2*)(k + (size_t)row * Kc))[lane];
  float sq = vq.x * vq.x + vq.y * vq.y;
  float sk = vk.x * vk.x + vk.y * vk.y;
#pragma unroll
  for (int m = 1; m < 64; m <<= 1) {
    sq += __shfl_xor(sq, m);
    sk += __shfl_xor(sk, m);
  }
  float rq = rsqrt_nr(sq + EPSc) * SCALEc;
  float rk = rsqrt_nr(sk + EPSc);
  ((float2*)(qn + (size_t)row * Kc))[lane] = make_float2(vq.x * rq, vq.y * rq);
  ((float2*)(kn + (size_t)row * Kc))[lane] = make_float2(vk.x * rk, vk.y * rk);
}

template <bool PRENORM>
__global__ __launch_bounds__(256) void gdn_scan(
    const float* __restrict__ q, const float* __restrict__ k,
    const float* __restrict__ v, const float* __restrict__ g,
    const float* __restrict__ beta, const float* __restrict__ s0,
    float* __restrict__ o, float* __restrict__ fs) {
  const int bid = blockIdx.x;
  const int vb = bid & 3;
  const int bh = bid >> 2;
  const int b = bh >> 4;
  const int h = bh & 15;
  const int tid = threadIdx.x;
  const int tk = tid & 7;
  const int tv = tid >> 3;
  const int vcol = vb * 32 + tv;
  const int k0 = tk * 16;
  float S[16];
  {
    const float* s0p = s0 + ((size_t)bh * Kc + k0) * Vc + vcol;
#pragma unroll
    for (int i = 0; i < 16; ++i) S[i] = s0p[(size_t)i * Vc];
  }
  const size_t qk_base = (size_t)b * Tc * Hc * Kc + (size_t)h * Kc + k0;
  const size_t v_base = (size_t)b * Tc * Hc * Vc + (size_t)h * Vc + vcol;
  const size_t gb_base = (size_t)b * Tc * Hc + h;
  const size_t qk_stride = (size_t)Hc * Kc;
  const size_t v_stride = (size_t)Hc * Vc;
  const size_t gb_stride = (size_t)Hc;
  float4 cq[4], ck[4];
  float cv, cg, cb;
  {
    const float* qrow = q + qk_base;
    const float* krow = k + qk_base;
#pragma unroll
    for (int i = 0; i < 4; ++i) {
      cq[i] = ((const float4*)qrow)[i];
      ck[i] = ((const float4*)krow)[i];
    }
    cv = v[v_base];
    cg = g[gb_base];
    cb = beta[gb_base];
  }
  for (int t = 0; t < Tc; ++t) {
    float4 nq[4], nk[4];
    float nv, ng, nb;
    {
      int tn = (t + 1 < Tc) ? (t + 1) : t;
      const float* qrow = q + qk_base + (size_t)tn * qk_stride;
      const float* krow = k + qk_base + (size_t)tn * qk_stride;
#pragma unroll
      for (int i = 0; i < 4; ++i) {
        nq[i] = ((const float4*)qrow)[i];
        nk[i] = ((const float4*)krow)[i];
      }
      nv = v[v_base + (size_t)tn * v_stride];
      ng = g[gb_base + (size_t)tn * gb_stride];
      nb = beta[gb_base + (size_t)tn * gb_stride];
    }
    float qn_[16], kn_[16];
#pragma unroll
    for (int i = 0; i < 4; ++i) {
      qn_[4 * i + 0] = cq[i].x; qn_[4 * i + 1] = cq[i].y;
      qn_[4 * i + 2] = cq[i].z; qn_[4 * i + 3] = cq[i].w;
      kn_[4 * i + 0] = ck[i].x; kn_[4 * i + 1] = ck[i].y;
      kn_[4 * i + 2] = ck[i].z; kn_[4 * i + 3] = ck[i].w;
    }
    if (!PRENORM) {
      float sq = 0.f, sk = 0.f;
#pragma unroll
      for (int i = 0; i < 16; ++i) {
        sq = fmaf(qn_[i], qn_[i], sq);
        sk = fmaf(kn_[i], kn_[i], sk);
      }
#pragma unroll
      for (int m = 1; m < 8; m <<= 1) {
        sq += __shfl_xor(sq, m);
        sk += __shfl_xor(sk, m);
      }
      float rq = rsqrt_nr(sq + EPSc) * SCALEc;
      float rk = rsqrt_nr(sk + EPSc);
#pragma unroll
      for (int i = 0; i < 16; ++i) {
        qn_[i] *= rq;
        kn_[i] *= rk;
      }
    }
    float eg = expf(cg);
    float p0 = 0.f, p1 = 0.f, p2 = 0.f, p3 = 0.f;
#pragma unroll
    for (int i = 0; i < 16; i += 4) {
      p0 = fmaf(kn_[i + 0], S[i + 0], p0);
      p1 = fmaf(kn_[i + 1], S[i + 1], p1);
      p2 = fmaf(kn_[i + 2], S[i + 2], p2);
      p3 = fmaf(kn_[i + 3], S[i + 3], p3);
    }
    float pred = (p0 + p1) + (p2 + p3);
#pragma unroll
    for (int m = 1; m < 8; m <<= 1) pred += __shfl_xor(pred, m);
    pred *= eg;
    float vadj = (cv - pred) * cb;
#pragma unroll
    for (int i = 0; i < 16; ++i) S[i] = fmaf(S[i], eg, kn_[i] * vadj);
    float o0 = 0.f, o1 = 0.f, o2 = 0.f, o3 = 0.f;
#pragma unroll
    for (int i = 0; i < 16; i += 4) {
      o0 = fmaf(qn_[i + 0], S[i + 0], o0);
      o1 = fmaf(qn_[i + 1], S[i + 1], o1);
      o2 = fmaf(qn_[i + 2], S[i + 2], o2);
      o3 = fmaf(qn_[i + 3], S[i + 3], o3);
    }
    float out = (o0 + o1) + (o2 + o3);
#pragma unroll
    for (int m = 1; m < 8; m <<= 1) out += __shfl_xor(out, m);
    if (tk == 0) o[((size_t)(b * Tc + t) * Hc + h) * Vc + vcol] = out;
#pragma unroll
    for (int i = 0; i < 4; ++i) {
      cq[i] = nq[i];
      ck[i] = nk[i];
    }
    cv = nv;
    cg = ng;
    cb = nb;
  }
  float* fsp = fs + ((size_t)bh * Kc + k0) * Vc + vcol;
#pragma unroll
  for (int i = 0; i < 16; ++i) fsp[(size_t)i * Vc] = S[i];
}

// =========================================================================
extern "C" void kernel_launch(void* const* d_in, const int* in_sizes, int n_in,
                              void* d_out, int out_size, void* d_ws, size_t ws_size,
                              hipStream_t stream) {
  const float* q = (const float*)d_in[0];
  const float* k = (const float*)d_in[1];
  const float* v = (const float*)d_in[2];
  const float* g = (const float*)d_in[3];
  const float* beta = (const float*)d_in[4];
  const float* s0 = (const float*)d_in[5];
  float* o = (float*)d_out;
  float* fs = o + (size_t)Bc * Tc * Hc * Vc;

  const size_t PLANE = (size_t)Bc * Hc * Tc * Kc;  // 16777216 elems
  // ws layout: qhi, qlo, khi, klo (ushort planes), Gc (f32), Tm (ushort)
  const size_t planes_b = 4 * PLANE * 2;                       // 134217728
  const size_t gc_b = (size_t)Bc * Hc * Tc * 4;                // 524288
  const size_t tm_b = (size_t)Bc * Hc * NCc * 4096 * 2;        // 16777216
  const size_t need_mfma = planes_b + gc_b + tm_b;             // ~151.5 MB
  const size_t need_prenorm = 2 * PLANE * sizeof(float);

  if (ws_size >= need_mfma) {
    char* wsb = (char*)d_ws;
    unsigned short* qhi = (unsigned short*)wsb;
    unsigned short* qlo = qhi + PLANE;
    unsigned short* khi = qlo + PLANE;
    unsigned short* klo = khi + PLANE;
    float* Gc = (float*)(wsb + planes_b);
    unsigned short* Tm = (unsigned short*)(wsb + planes_b + gc_b);

    hipFuncSetAttribute(reinterpret_cast<const void*>(k_tmat),
                        hipFuncAttributeMaxDynamicSharedMemorySize, 52224);
    hipFuncSetAttribute(reinterpret_cast<const void*>(gdn3),
                        hipFuncAttributeMaxDynamicSharedMemorySize, 141824);

    norm_planes<<<(Bc * Tc * Hc) / 4, 256, 0, stream>>>(
        q, k, (unsigned int*)qhi, (unsigned int*)qlo, (unsigned int*)khi, (unsigned int*)klo);
    k_gates<<<(Bc * Hc * NCc) / 4, 256, 0, stream>>>(g, Gc);
    k_tmat<<<Bc * Hc * NCc, 256, 52224, stream>>>(khi, klo, Gc, beta, (unsigned int*)Tm);
    gdn3<<<Bc * Hc * 4, 256, 141824, stream>>>(qhi, qlo, khi, klo, Tm, Gc, v, beta, s0, o, fs);
  } else if (ws_size >= need_prenorm) {
    float* qn = (float*)d_ws;
    float* kn = qn + PLANE;
    norm_qk<<<(Bc * Tc * Hc) / 4, 256, 0, stream>>>(q, k, qn, kn);
    gdn_scan<true><<<Bc * Hc * 4, 256, 0, stream>>>(qn, kn, v, g, beta, s0, o, fs);
  } else {
    gdn_scan<false><<<Bc * Hc * 4, 256, 0, stream>>>(q, k, v, g, beta, s0, o, fs);
  }
}